// Round 10
// baseline (169.902 us; speedup 1.0000x reference)
//
#include <hip/hip_runtime.h>
#include <math.h>

// The position/mask chain must replicate the numpy fp32 reference bit-exactly
// (no FMA contraction): the entry-face validity test (pos > -1) is knife-edge
// for every hitting ray. Sample math is u8-quantized and may contract.
#pragma clang fp contract(off)

#define DT 0.03125f
#define INV_DT 32.0f
#define NSTEPS 111

#if defined(__has_builtin)
#if __has_builtin(__builtin_amdgcn_udot4)
#define HAVE_UDOT4 1
#endif
#endif

__device__ __forceinline__ unsigned udot4(unsigned a, unsigned b) {
#ifdef HAVE_UDOT4
    return __builtin_amdgcn_udot4(a, b, 0u, false);
#else
    return (a & 0xffu) * (b & 0xffu)
         + ((a >> 8) & 0xffu) * ((b >> 8) & 0xffu)
         + ((a >> 16) & 0xffu) * ((b >> 16) & 0xffu)
         + ((a >> 24) & 0xffu) * ((b >> 24) & 0xffu);
#endif
}

// ---------------- u8 stencil-pair packing ----------------
// Entry (z,y,x) = 16B = 4 dwords (r,g,b,sigma); dword bytes:
//   [c(x0,y0), c(x1,y0), c(x0,y1), c(x1,y1)]  (x1=min(x+1,D-1), y1=min(y+1,D-1))
// Trilinear stencil = entry at z0 + entry at z0+1: 2 gathers/step.

__device__ __forceinline__ unsigned q8(float v) {
    return __float2uint_rn(fminf(fmaxf(v, 0.0f), 1.0f) * 255.0f);
}

// Fast repack with cross-lane neighbor fetch: the x+4 element needed for the
// last voxel of each 4-chunk is lane i+1's va.x (8 shfls replace 8 global
// loads -> 12 VMEM instr/thread instead of 20; repack was VMEM-instr-bound).
// Valid when chunks never straddle waves except at row ends:
//   D%4==0 && 64 % (D/4) == 0 && chunks-per-batch % 256 == 0.
__global__ __launch_bounds__(256) void repack_u8x4_shfl_kernel(
        const float* __restrict__ vol, uint4* __restrict__ out,
        long spatial, int D) {
    long chunk = (long)blockIdx.x * 256 + threadIdx.x;
    long b = blockIdx.y;
    long s = chunk << 2;
    int zs = D * D;
    int z = (int)(s / zs);
    int rem = (int)(s - (long)z * zs);
    int y = rem / D;
    int x0 = rem - y * D;           // chunk never straddles a row (D%4==0)
    int y1 = (y < D - 1) ? y + 1 : y;
    bool last = (x0 + 4 >= D);      // row-end: x+1 clamps to D-1 (= va.w)

    const float* base = vol + b * 4 * spatial;
    uint4 e[4];
    #pragma unroll
    for (int ci = 0; ci < 4; ++ci) {
        const float* pa = base + (long)ci * spatial + (long)z * zs + y * D + x0;
        const float* pb = base + (long)ci * spatial + (long)z * zs + y1 * D + x0;
        float4 va = *(const float4*)pa;
        float4 vb = *(const float4*)pb;
        float na_sh = __shfl_down(va.x, 1, 64);   // lane i+1's first element
        float nb_sh = __shfl_down(vb.x, 1, 64);
        float na = last ? va.w : na_sh;           // row-end lanes override (also
        float nb = last ? vb.w : nb_sh;           // covers wave-boundary lanes)
        float ra[5] = {va.x, va.y, va.z, va.w, na};
        float rb[5] = {vb.x, vb.y, vb.z, vb.w, nb};
        #pragma unroll
        for (int k = 0; k < 4; ++k) {
            unsigned d = q8(ra[k]) | (q8(ra[k + 1]) << 8) |
                         (q8(rb[k]) << 16) | (q8(rb[k + 1]) << 24);
            ((unsigned*)&e[k])[ci] = d;
        }
    }
    uint4* o = out + b * spatial + s;
    o[0] = e[0]; o[1] = e[1]; o[2] = e[2]; o[3] = e[3];
}

// Previous fast repack (scalar neighbor loads). Requires D % 4 == 0.
__global__ __launch_bounds__(256) void repack_u8x4_kernel(const float* __restrict__ vol,
                                                          uint4* __restrict__ out,
                                                          long spatial, int D) {
    long chunk = (long)blockIdx.x * blockDim.x + threadIdx.x;
    long nchunks = spatial >> 2;
    if (chunk >= nchunks) return;
    long b = blockIdx.y;
    long s = chunk << 2;
    int zs = D * D;
    int z = (int)(s / zs);
    int rem = (int)(s - (long)z * zs);
    int y = rem / D;
    int x0 = rem - y * D;
    int y1 = (y < D - 1) ? y + 1 : y;

    const float* base = vol + b * 4 * spatial;
    uint4 e[4];
    #pragma unroll
    for (int ci = 0; ci < 4; ++ci) {
        const float* pa = base + (long)ci * spatial + (long)z * zs + y * D + x0;
        const float* pb = base + (long)ci * spatial + (long)z * zs + y1 * D + x0;
        float4 va = *(const float4*)pa;
        float4 vb = *(const float4*)pb;
        bool last = (x0 + 4 >= D);
        float na = last ? pa[3] : pa[4];
        float nb = last ? pb[3] : pb[4];
        float ra[5] = {va.x, va.y, va.z, va.w, na};
        float rb[5] = {vb.x, vb.y, vb.z, vb.w, nb};
        #pragma unroll
        for (int k = 0; k < 4; ++k) {
            unsigned d = q8(ra[k]) | (q8(ra[k + 1]) << 8) |
                         (q8(rb[k]) << 16) | (q8(rb[k + 1]) << 24);
            ((unsigned*)&e[k])[ci] = d;
        }
    }
    uint4* o = out + b * spatial + s;
    o[0] = e[0]; o[1] = e[1]; o[2] = e[2]; o[3] = e[3];
}

// Generic repack: one entry per thread (any D).
__global__ __launch_bounds__(256) void repack_u8_kernel(const float* __restrict__ vol,
                                                        uint4* __restrict__ out,
                                                        long total, long spatial, int D) {
    long idx = (long)blockIdx.x * blockDim.x + threadIdx.x;
    if (idx >= total) return;
    long b = idx / spatial;
    long s = idx - b * spatial;
    int zs = D * D;
    int z = (int)(s / zs);
    int rem = (int)(s - (long)z * zs);
    int y = rem / D;
    int x = rem - y * D;
    int x1 = (x < D - 1) ? x + 1 : x;
    int y1 = (y < D - 1) ? y + 1 : y;
    const float* base = vol + b * 4 * spatial;
    uint4 e;
    #pragma unroll
    for (int ci = 0; ci < 4; ++ci) {
        const float* p = base + (long)ci * spatial + (long)z * zs;
        unsigned d = q8(p[y * D + x]) | (q8(p[y * D + x1]) << 8) |
                     (q8(p[y1 * D + x]) << 16) | (q8(p[y1 * D + x1]) << 24);
        ((unsigned*)&e)[ci] = d;
    }
    out[idx] = e;
}

// ---------------- shared ray setup (bit-exact) ----------------

struct Ray {
    float posx, posy, posz;
    float stx, sty, stz;
    int n;   // conservative bound: steps >= n are provably invalid
};

__device__ __forceinline__ Ray ray_setup(const float* __restrict__ camrot,
                                         const float* __restrict__ campos,
                                         const float* __restrict__ focal,
                                         const float* __restrict__ princpt,
                                         const float* __restrict__ pixelcoords,
                                         int b, int y, int x, int H, int W) {
#pragma clang fp contract(off)
    long pidx = (((long)b * H + y) * W + x) * 2;
    float px = pixelcoords[pidx];
    float py = pixelcoords[pidx + 1];
    const float* R = camrot + b * 9;
    float cpx = campos[b * 3 + 0], cpy = campos[b * 3 + 1], cpz = campos[b * 3 + 2];
    float flx = focal[b * 2 + 0], fly = focal[b * 2 + 1];
    float prx = princpt[b * 2 + 0], pry = princpt[b * 2 + 1];

    float rx = (px - prx) / flx;
    float ry = (py - pry) / fly;
    float rz = 1.0f;
    float dx = R[0] * rx + R[3] * ry + R[6] * rz;
    float dy = R[1] * rx + R[4] * ry + R[7] * rz;
    float dz = R[2] * rx + R[5] * ry + R[8] * rz;
    float ss = dx * dx;
    ss = ss + dy * dy;
    ss = ss + dz * dz;
    float nrm = sqrtf(ss);
    dx = dx / nrm; dy = dy / nrm; dz = dz / nrm;

    float t1x = (-1.0f - cpx) / dx, t2x = (1.0f - cpx) / dx;
    float t1y = (-1.0f - cpy) / dy, t2y = (1.0f - cpy) / dy;
    float t1z = (-1.0f - cpz) / dz, t2z = (1.0f - cpz) / dz;
    float tmin = fmaxf(fminf(t1x, t2x), fmaxf(fminf(t1y, t2y), fminf(t1z, t2z)));
    float tmax = fminf(fmaxf(t1x, t2x), fminf(fmaxf(t1y, t2y), fmaxf(t1z, t2z)));
    bool hit = tmin < tmax;
    float t0 = fmaxf(hit ? tmin : 0.0f, 0.0f);

    Ray r;
    r.posx = cpx + dx * t0;
    r.posy = cpy + dy * t0;
    r.posz = cpz + dz * t0;
    r.stx = dx * DT; r.sty = dy * DT; r.stz = dz * DT;

    float span = (tmax - t0) * INV_DT + 4.0f;
    span = fminf(span, (float)NSTEPS);
    r.n = (hit && span > 0.0f) ? (int)span : 0;
    return r;
}

// per-step sample helpers (approximate path; u8-quantized anyway)
#define STEP_ADDR(PX, PY, PZ, IXV, IYV, IZV, FZV, WPV)                          \
    do {                                                                        \
        float gx_, gy_, gz_;                                                    \
        {                                                                       \
        _Pragma("clang fp contract(fast)")                                      \
            gx_ = PX * gsc + gsc; gy_ = PY * gsc + gsc; gz_ = PZ * gsc + gsc;   \
        }                                                                       \
        IXV = (int)floorf(gx_); IXV = min(max(IXV, 0), D - 2);                  \
        IYV = (int)floorf(gy_); IYV = min(max(IYV, 0), D - 2);                  \
        IZV = (int)floorf(gz_); IZV = min(max(IZV, 0), D - 2);                  \
        float fx_ = fminf(fmaxf(gx_ - (float)IXV, 0.0f), 1.0f);                 \
        float fy_ = fminf(fmaxf(gy_ - (float)IYV, 0.0f), 1.0f);                 \
        FZV = fminf(fmaxf(gz_ - (float)IZV, 0.0f), 1.0f);                       \
        int wx1_ = (int)(fx_ * 255.0f + 0.5f);                                  \
        int wy1_ = (int)(fy_ * 255.0f + 0.5f);                                  \
        int wx0_ = 255 - wx1_, wy0_ = 255 - wy1_;                               \
        unsigned p00_ = (unsigned)((wx0_ * wy0_ + 128) >> 8);                   \
        unsigned p10_ = (unsigned)((wx1_ * wy0_ + 128) >> 8);                   \
        unsigned p01_ = (unsigned)((wx0_ * wy1_ + 128) >> 8);                   \
        unsigned p11_ = (unsigned)((wx1_ * wy1_ + 128) >> 8);                   \
        WPV = p00_ | (p10_ << 8) | (p01_ << 16) | (p11_ << 24);                 \
    } while (0)

#define STEP_CONSUME(AV, BV, WPV, FZV, MV, AR, AG, AB, AL)                      \
    do {                                                                        \
        float rA_ = (float)udot4(AV.x, WPV), rB_ = (float)udot4(BV.x, WPV);     \
        float gA_ = (float)udot4(AV.y, WPV), gB_ = (float)udot4(BV.y, WPV);     \
        float bA_ = (float)udot4(AV.z, WPV), bB_ = (float)udot4(BV.z, WPV);     \
        float sA_ = (float)udot4(AV.w, WPV), sB_ = (float)udot4(BV.w, WPV);     \
        float rS_, gS_, bS_, sw_;                                               \
        {                                                                       \
        _Pragma("clang fp contract(fast)")                                      \
            rS_ = rA_ + FZV * (rB_ - rA_);                                      \
            gS_ = gA_ + FZV * (gB_ - gA_);                                      \
            bS_ = bA_ + FZV * (bB_ - bA_);                                      \
            sw_ = (sA_ + FZV * (sB_ - sA_)) * inv;                              \
        }                                                                       \
        float contrib_ = (fminf(AL + sw_ * DT, 1.0f) - AL) * MV;                \
        {                                                                       \
        _Pragma("clang fp contract(fast)")                                      \
            AR = AR + rS_ * contrib_;                                           \
            AG = AG + gS_ * contrib_;                                           \
            AB = AB + bS_ * contrib_;                                           \
        }                                                                       \
        AL = AL + contrib_;                                                     \
    } while (0)

// ---------------- march: 2 independent rays per thread ----------------
// Intra-ray software pipelining is collapsed by the scheduler (R3/R4/R6);
// two rays are independent DAGs, so the compiler keeps 4 loads in flight and
// issues ray-1 VALU under ray-0's load stall. 16x8 block covers a 16x16 tile
// (thread handles y and y+8).

template <int DD>
__global__ __launch_bounds__(128) void raymarch_dot2_kernel(
        const float* __restrict__ camrot, const float* __restrict__ campos,
        const float* __restrict__ focal, const float* __restrict__ princpt,
        const float* __restrict__ pixelcoords, const uint4* __restrict__ vol,
        float* __restrict__ out, int B, int H, int W, int Drt) {
#pragma clang fp contract(off)
    const int D = (DD > 0) ? DD : Drt;
    int x = blockIdx.x * 16 + threadIdx.x;
    int y0 = blockIdx.y * 16 + threadIdx.y;
    int y1 = y0 + 8;
    int b = blockIdx.z;
    if (x >= W || y0 >= H) return;
    bool live1 = (y1 < H);

    Ray ra = ray_setup(camrot, campos, focal, princpt, pixelcoords, b, y0, x, H, W);
    Ray rb;
    if (live1) {
        rb = ray_setup(camrot, campos, focal, princpt, pixelcoords, b, y1, x, H, W);
    } else {
        rb.posx = rb.posy = rb.posz = 2.0f;  // outside -> mask always 0
        rb.stx = rb.sty = rb.stz = 0.0f;
        rb.n = 0;
    }
    int nmax = (ra.n > rb.n) ? ra.n : rb.n;

    const float gsc = 0.5f * (float)(D - 1);
    const float inv = 1.0f / (255.0f * 255.0f);
    const int zs = D * D;
    const uint4* vp = vol + (long)b * ((long)zs * D);

    float a0r = 0.0f, a0g = 0.0f, a0b = 0.0f, al0 = 0.0f;
    float a1r = 0.0f, a1g = 0.0f, a1b = 0.0f, al1 = 0.0f;
    float p0x = ra.posx, p0y = ra.posy, p0z = ra.posz;
    float p1x = rb.posx, p1y = rb.posy, p1z = rb.posz;

    for (int s = 0; s < nmax; ++s) {
        // exact masks (contract-off file default, reference op order)
        bool in0 = (p0x > -1.0f) && (p0x < 1.0f) && (p0y > -1.0f) &&
                   (p0y < 1.0f) && (p0z > -1.0f) && (p0z < 1.0f);
        bool in1 = (p1x > -1.0f) && (p1x < 1.0f) && (p1y > -1.0f) &&
                   (p1y < 1.0f) && (p1z > -1.0f) && (p1z < 1.0f);
        float m0 = in0 ? 1.0f : 0.0f;
        float m1 = in1 ? 1.0f : 0.0f;

        int ix0, iy0, iz0, ix1, iy1, iz1;
        float fz0, fz1;
        unsigned wp0, wp1;
        STEP_ADDR(p0x, p0y, p0z, ix0, iy0, iz0, fz0, wp0);
        STEP_ADDR(p1x, p1y, p1z, ix1, iy1, iz1, fz1, wp1);

        const uint4* q0 = vp + (iz0 * zs + iy0 * D + ix0);
        const uint4* q1 = vp + (iz1 * zs + iy1 * D + ix1);
        uint4 A0 = q0[0];
        uint4 B0 = q0[zs];
        uint4 A1 = q1[0];
        uint4 B1 = q1[zs];

        STEP_CONSUME(A0, B0, wp0, fz0, m0, a0r, a0g, a0b, al0);
        STEP_CONSUME(A1, B1, wp1, fz1, m1, a1r, a1g, a1b, al1);

        p0x = p0x + ra.stx; p0y = p0y + ra.sty; p0z = p0z + ra.stz;  // exact chains
        p1x = p1x + rb.stx; p1y = p1y + rb.sty; p1z = p1z + rb.stz;
    }

    long hw = (long)H * W;
    long o0 = (long)b * 4 * hw + (long)y0 * W + x;
    out[o0] = a0r * inv;
    out[o0 + hw] = a0g * inv;
    out[o0 + 2 * hw] = a0b * inv;
    out[o0 + 3 * hw] = al0;
    if (live1) {
        long o1 = (long)b * 4 * hw + (long)y1 * W + x;
        out[o1] = a1r * inv;
        out[o1 + hw] = a1g * inv;
        out[o1 + 2 * hw] = a1b * inv;
        out[o1 + 3 * hw] = al1;
    }
}

// ---------------- fallback: whole-ray march on original fp32 layout ----------

__global__ __launch_bounds__(256) void raymarch_simple_kernel(
        const float* __restrict__ camrot, const float* __restrict__ campos,
        const float* __restrict__ focal, const float* __restrict__ princpt,
        const float* __restrict__ pixelcoords, const float* __restrict__ vol,
        float* __restrict__ out, int B, int H, int W, int D) {
#pragma clang fp contract(off)
    int x = blockIdx.x * blockDim.x + threadIdx.x;
    int y = blockIdx.y * blockDim.y + threadIdx.y;
    int b = blockIdx.z;
    if (x >= W || y >= H) return;

    Ray r = ray_setup(camrot, campos, focal, princpt, pixelcoords, b, y, x, H, W);

    float accr = 0.0f, accg = 0.0f, accb = 0.0f, alpha = 0.0f;
    float gmax = (float)(D - 1);
    long spatial = (long)D * D * D;
    long zstride = (long)D * D;
    const float* vb = vol + (long)b * 4 * spatial;
    float pxx = r.posx, pyy = r.posy, pzz = r.posz;

    for (int s = 0; s < r.n; ++s) {
        bool inside = (pxx > -1.0f) && (pxx < 1.0f) && (pyy > -1.0f) &&
                      (pyy < 1.0f) && (pzz > -1.0f) && (pzz < 1.0f);
        float m = inside ? 1.0f : 0.0f;
        float gx = fminf(fmaxf((pxx + 1.0f) * 0.5f * gmax, 0.0f), gmax);
        float gy = fminf(fmaxf((pyy + 1.0f) * 0.5f * gmax, 0.0f), gmax);
        float gz = fminf(fmaxf((pzz + 1.0f) * 0.5f * gmax, 0.0f), gmax);
        int ix0 = (int)floorf(gx); if (ix0 > D - 2) ix0 = D - 2;
        int iy0 = (int)floorf(gy); if (iy0 > D - 2) iy0 = D - 2;
        int iz0 = (int)floorf(gz); if (iz0 > D - 2) iz0 = D - 2;
        float fx = gx - (float)ix0;
        float fy = gy - (float)iy0;
        float fz = gz - (float)iz0;

        long s000 = (long)iz0 * zstride + (long)iy0 * D + ix0;
        float c[8][4];
        const long offs[8] = {s000, s000 + 1, s000 + D, s000 + D + 1,
                              s000 + zstride, s000 + zstride + 1,
                              s000 + zstride + D, s000 + zstride + D + 1};
        #pragma unroll
        for (int k = 0; k < 8; ++k) {
            c[k][0] = vb[offs[k]];
            c[k][1] = vb[offs[k] + spatial];
            c[k][2] = vb[offs[k] + 2 * spatial];
            c[k][3] = vb[offs[k] + 3 * spatial];
        }
        float wa = 1.0f - fx, wb = 1.0f - fy, wc = 1.0f - fz;
        float samp[4];
        #pragma unroll
        for (int ci = 0; ci < 4; ++ci) {
            float c00 = c[0][ci] * wa + c[1][ci] * fx;
            float c01 = c[2][ci] * wa + c[3][ci] * fx;
            float c10 = c[4][ci] * wa + c[5][ci] * fx;
            float c11 = c[6][ci] * wa + c[7][ci] * fx;
            float c0 = c00 * wb + c01 * fy;
            float c1 = c10 * wb + c11 * fy;
            samp[ci] = c0 * wc + c1 * fz;
        }
        float contrib = (fminf(alpha + samp[3] * DT, 1.0f) - alpha) * m;
        accr = accr + samp[0] * contrib;
        accg = accg + samp[1] * contrib;
        accb = accb + samp[2] * contrib;
        alpha = alpha + contrib;
        pxx = pxx + r.stx; pyy = pyy + r.sty; pzz = pzz + r.stz;
    }

    long hw = (long)H * W;
    long o = (long)b * 4 * hw + (long)y * W + x;
    out[o] = accr;
    out[o + hw] = accg;
    out[o + 2 * hw] = accb;
    out[o + 3 * hw] = alpha;
}

extern "C" void kernel_launch(void* const* d_in, const int* in_sizes, int n_in,
                              void* d_out, int out_size, void* d_ws, size_t ws_size,
                              hipStream_t stream) {
    const float* camrot = (const float*)d_in[0];
    const float* campos = (const float*)d_in[1];
    const float* focal = (const float*)d_in[2];
    const float* princpt = (const float*)d_in[3];
    const float* pixelcoords = (const float*)d_in[4];
    const float* volume = (const float*)d_in[5];
    float* out = (float*)d_out;

    int B = in_sizes[0] / 9;
    long spatial = (long)in_sizes[5] / (B * 4);  // D^3
    int D = (int)lround(cbrt((double)spatial));
    while ((long)D * D * D > spatial) D--;
    while ((long)(D + 1) * (D + 1) * (D + 1) <= spatial) D++;
    long hw = (long)in_sizes[4] / (B * 2);
    int H = (int)lround(sqrt((double)hw));
    int W = H;

    size_t vol_bytes = (size_t)B * spatial * sizeof(uint4);

    if (ws_size >= vol_bytes && D >= 2) {
        uint4* vol8 = (uint4*)d_ws;
        long nchunks = spatial >> 2;
        bool shfl_ok = ((D & 3) == 0) && ((64 % (D / 4)) == 0) &&
                       ((nchunks % 256) == 0);
        if (shfl_ok) {
            dim3 rgrd((unsigned)(nchunks / 256), B, 1);
            repack_u8x4_shfl_kernel<<<rgrd, dim3(256), 0, stream>>>(volume, vol8,
                                                                    spatial, D);
        } else if ((D & 3) == 0) {
            dim3 rgrd((unsigned)((nchunks + 255) / 256), B, 1);
            repack_u8x4_kernel<<<rgrd, dim3(256), 0, stream>>>(volume, vol8, spatial, D);
        } else {
            long total = (long)B * spatial;
            repack_u8_kernel<<<dim3((unsigned)((total + 255) / 256)), dim3(256), 0,
                               stream>>>(volume, vol8, total, spatial, D);
        }
        dim3 blk(16, 8, 1);
        dim3 grd((W + 15) / 16, (H + 15) / 16, B);
        if (D == 128) {
            raymarch_dot2_kernel<128><<<grd, blk, 0, stream>>>(
                camrot, campos, focal, princpt, pixelcoords, vol8, out, B, H, W, D);
        } else {
            raymarch_dot2_kernel<0><<<grd, blk, 0, stream>>>(
                camrot, campos, focal, princpt, pixelcoords, vol8, out, B, H, W, D);
        }
    } else {
        dim3 blk(16, 16, 1);
        dim3 grd((W + 15) / 16, (H + 15) / 16, B);
        raymarch_simple_kernel<<<grd, blk, 0, stream>>>(camrot, campos, focal, princpt,
                                                        pixelcoords, volume,
                                                        out, B, H, W, D);
    }
}

// Round 11
// 154.306 us; speedup vs baseline: 1.1011x; 1.1011x over previous
//
#include <hip/hip_runtime.h>
#include <math.h>

// The position/mask chain must replicate the numpy fp32 reference bit-exactly
// (no FMA contraction): the entry-face validity test (pos > -1) is knife-edge
// for every hitting ray. Sample math is u8-quantized and may contract.
#pragma clang fp contract(off)

#define DT 0.03125f
#define INV_DT 32.0f
#define NSTEPS 111

#if defined(__has_builtin)
#if __has_builtin(__builtin_amdgcn_udot4)
#define HAVE_UDOT4 1
#endif
#endif

__device__ __forceinline__ unsigned udot4(unsigned a, unsigned b) {
#ifdef HAVE_UDOT4
    return __builtin_amdgcn_udot4(a, b, 0u, false);
#else
    return (a & 0xffu) * (b & 0xffu)
         + ((a >> 8) & 0xffu) * ((b >> 8) & 0xffu)
         + ((a >> 16) & 0xffu) * ((b >> 16) & 0xffu)
         + ((a >> 24) & 0xffu) * ((b >> 24) & 0xffu);
#endif
}

// ---------------- u8 stencil-pair packing ----------------
// Entry (z,y,x) = 16B = 4 dwords (r,g,b,sigma); dword bytes:
//   [c(x0,y0), c(x1,y0), c(x0,y1), c(x1,y1)]  (x1=min(x+1,D-1), y1=min(y+1,D-1))
// Trilinear stencil = entry at z0 + entry at z0+1: 2 gathers/step.

__device__ __forceinline__ unsigned q8(float v) {
    return __float2uint_rn(fminf(fmaxf(v, 0.0f), 1.0f) * 255.0f);
}

// Fast repack with cross-lane neighbor fetch (R10 win: repack was
// VMEM-instruction-bound; 8 shfls replace 8 global loads -> 12 VMEM/thread).
// Valid when chunks never straddle waves except at row ends:
//   D%4==0 && 64 % (D/4) == 0 && chunks-per-batch % 256 == 0.
__global__ __launch_bounds__(256) void repack_u8x4_shfl_kernel(
        const float* __restrict__ vol, uint4* __restrict__ out,
        long spatial, int D) {
    long chunk = (long)blockIdx.x * 256 + threadIdx.x;
    long b = blockIdx.y;
    long s = chunk << 2;
    int zs = D * D;
    int z = (int)(s / zs);
    int rem = (int)(s - (long)z * zs);
    int y = rem / D;
    int x0 = rem - y * D;           // chunk never straddles a row (D%4==0)
    int y1 = (y < D - 1) ? y + 1 : y;
    bool last = (x0 + 4 >= D);      // row-end: x+1 clamps to D-1 (= va.w)

    const float* base = vol + b * 4 * spatial;
    uint4 e[4];
    #pragma unroll
    for (int ci = 0; ci < 4; ++ci) {
        const float* pa = base + (long)ci * spatial + (long)z * zs + y * D + x0;
        const float* pb = base + (long)ci * spatial + (long)z * zs + y1 * D + x0;
        float4 va = *(const float4*)pa;
        float4 vb = *(const float4*)pb;
        float na_sh = __shfl_down(va.x, 1, 64);   // lane i+1's first element
        float nb_sh = __shfl_down(vb.x, 1, 64);
        float na = last ? va.w : na_sh;           // row-end lanes override (also
        float nb = last ? vb.w : nb_sh;           // covers wave-boundary lanes)
        float ra[5] = {va.x, va.y, va.z, va.w, na};
        float rb[5] = {vb.x, vb.y, vb.z, vb.w, nb};
        #pragma unroll
        for (int k = 0; k < 4; ++k) {
            unsigned d = q8(ra[k]) | (q8(ra[k + 1]) << 8) |
                         (q8(rb[k]) << 16) | (q8(rb[k + 1]) << 24);
            ((unsigned*)&e[k])[ci] = d;
        }
    }
    uint4* o = out + b * spatial + s;
    o[0] = e[0]; o[1] = e[1]; o[2] = e[2]; o[3] = e[3];
}

// Fast repack without shfl (scalar neighbor loads). Requires D % 4 == 0.
__global__ __launch_bounds__(256) void repack_u8x4_kernel(const float* __restrict__ vol,
                                                          uint4* __restrict__ out,
                                                          long spatial, int D) {
    long chunk = (long)blockIdx.x * blockDim.x + threadIdx.x;
    long nchunks = spatial >> 2;
    if (chunk >= nchunks) return;
    long b = blockIdx.y;
    long s = chunk << 2;
    int zs = D * D;
    int z = (int)(s / zs);
    int rem = (int)(s - (long)z * zs);
    int y = rem / D;
    int x0 = rem - y * D;
    int y1 = (y < D - 1) ? y + 1 : y;

    const float* base = vol + b * 4 * spatial;
    uint4 e[4];
    #pragma unroll
    for (int ci = 0; ci < 4; ++ci) {
        const float* pa = base + (long)ci * spatial + (long)z * zs + y * D + x0;
        const float* pb = base + (long)ci * spatial + (long)z * zs + y1 * D + x0;
        float4 va = *(const float4*)pa;
        float4 vb = *(const float4*)pb;
        bool last = (x0 + 4 >= D);
        float na = last ? pa[3] : pa[4];
        float nb = last ? pb[3] : pb[4];
        float ra[5] = {va.x, va.y, va.z, va.w, na};
        float rb[5] = {vb.x, vb.y, vb.z, vb.w, nb};
        #pragma unroll
        for (int k = 0; k < 4; ++k) {
            unsigned d = q8(ra[k]) | (q8(ra[k + 1]) << 8) |
                         (q8(rb[k]) << 16) | (q8(rb[k + 1]) << 24);
            ((unsigned*)&e[k])[ci] = d;
        }
    }
    uint4* o = out + b * spatial + s;
    o[0] = e[0]; o[1] = e[1]; o[2] = e[2]; o[3] = e[3];
}

// Generic repack: one entry per thread (any D).
__global__ __launch_bounds__(256) void repack_u8_kernel(const float* __restrict__ vol,
                                                        uint4* __restrict__ out,
                                                        long total, long spatial, int D) {
    long idx = (long)blockIdx.x * blockDim.x + threadIdx.x;
    if (idx >= total) return;
    long b = idx / spatial;
    long s = idx - b * spatial;
    int zs = D * D;
    int z = (int)(s / zs);
    int rem = (int)(s - (long)z * zs);
    int y = rem / D;
    int x = rem - y * D;
    int x1 = (x < D - 1) ? x + 1 : x;
    int y1 = (y < D - 1) ? y + 1 : y;
    const float* base = vol + b * 4 * spatial;
    uint4 e;
    #pragma unroll
    for (int ci = 0; ci < 4; ++ci) {
        const float* p = base + (long)ci * spatial + (long)z * zs;
        unsigned d = q8(p[y * D + x]) | (q8(p[y * D + x1]) << 8) |
                     (q8(p[y1 * D + x]) << 16) | (q8(p[y1 * D + x1]) << 24);
        ((unsigned*)&e)[ci] = d;
    }
    out[idx] = e;
}

// ---------------- shared ray setup (bit-exact) ----------------

struct Ray {
    float posx, posy, posz;
    float stx, sty, stz;
    int n;   // conservative bound: steps >= n are provably invalid
};

__device__ __forceinline__ Ray ray_setup(const float* __restrict__ camrot,
                                         const float* __restrict__ campos,
                                         const float* __restrict__ focal,
                                         const float* __restrict__ princpt,
                                         const float* __restrict__ pixelcoords,
                                         int b, int y, int x, int H, int W) {
#pragma clang fp contract(off)
    long pidx = (((long)b * H + y) * W + x) * 2;
    float px = pixelcoords[pidx];
    float py = pixelcoords[pidx + 1];
    const float* R = camrot + b * 9;
    float cpx = campos[b * 3 + 0], cpy = campos[b * 3 + 1], cpz = campos[b * 3 + 2];
    float flx = focal[b * 2 + 0], fly = focal[b * 2 + 1];
    float prx = princpt[b * 2 + 0], pry = princpt[b * 2 + 1];

    float rx = (px - prx) / flx;
    float ry = (py - pry) / fly;
    float rz = 1.0f;
    float dx = R[0] * rx + R[3] * ry + R[6] * rz;
    float dy = R[1] * rx + R[4] * ry + R[7] * rz;
    float dz = R[2] * rx + R[5] * ry + R[8] * rz;
    float ss = dx * dx;
    ss = ss + dy * dy;
    ss = ss + dz * dz;
    float nrm = sqrtf(ss);
    dx = dx / nrm; dy = dy / nrm; dz = dz / nrm;

    float t1x = (-1.0f - cpx) / dx, t2x = (1.0f - cpx) / dx;
    float t1y = (-1.0f - cpy) / dy, t2y = (1.0f - cpy) / dy;
    float t1z = (-1.0f - cpz) / dz, t2z = (1.0f - cpz) / dz;
    float tmin = fmaxf(fminf(t1x, t2x), fmaxf(fminf(t1y, t2y), fminf(t1z, t2z)));
    float tmax = fminf(fmaxf(t1x, t2x), fminf(fmaxf(t1y, t2y), fmaxf(t1z, t2z)));
    bool hit = tmin < tmax;
    float t0 = fmaxf(hit ? tmin : 0.0f, 0.0f);

    Ray r;
    r.posx = cpx + dx * t0;
    r.posy = cpy + dy * t0;
    r.posz = cpz + dz * t0;
    r.stx = dx * DT; r.sty = dy * DT; r.stz = dz * DT;

    // valid step s needs t0 + s*DT < tmax; +4 slack dwarfs fp drift over <=111
    // rounded adds. NaN span -> fminf selects NSTEPS (conservative). Steps in
    // [n, NSTEPS) are provably invalid (mask would be 0) so skipping is exact.
    float span = (tmax - t0) * INV_DT + 4.0f;
    span = fminf(span, (float)NSTEPS);
    r.n = (hit && span > 0.0f) ? (int)span : 0;
    return r;
}

// ---------------- march: u8 stencil-pair volume + v_dot4 sampling ----------
// (R9 structure verbatim: single ray/thread, 256-thread blocks, 8 waves/CU.
//  Do NOT re-attempt intra-thread pipelining or multi-ray ILP — the scheduler
//  collapses the buffers and serializes; measured 4x in R3/R4/R6/R10.)

template <int DD>
__global__ __launch_bounds__(256, 2) void raymarch_dot_kernel(
        const float* __restrict__ camrot, const float* __restrict__ campos,
        const float* __restrict__ focal, const float* __restrict__ princpt,
        const float* __restrict__ pixelcoords, const uint4* __restrict__ vol,
        float* __restrict__ out, int B, int H, int W, int Drt) {
#pragma clang fp contract(off)
    const int D = (DD > 0) ? DD : Drt;
    int x = blockIdx.x * 16 + threadIdx.x;
    int y = blockIdx.y * 16 + threadIdx.y;
    int b = blockIdx.z;
    if (x >= W || y >= H) return;

    Ray r = ray_setup(camrot, campos, focal, princpt, pixelcoords, b, y, x, H, W);

    float accr = 0.0f, accg = 0.0f, accb = 0.0f, alpha = 0.0f;
    const float gsc = 0.5f * (float)(D - 1);        // g = pos*gsc + gsc
    const float inv = 1.0f / (255.0f * 255.0f);
    const int zs = D * D;
    const uint4* vp = vol + (long)b * ((long)zs * D);
    float pxx = r.posx, pyy = r.posy, pzz = r.posz;
    float stx = r.stx, sty = r.sty, stz = r.stz;

    for (int s = 0; s < r.n; ++s) {
        // exact mask (file-default contract(off), same op order as reference)
        bool inside = (pxx > -1.0f) && (pxx < 1.0f) && (pyy > -1.0f) &&
                      (pyy < 1.0f) && (pzz > -1.0f) && (pzz < 1.0f);
        float m = inside ? 1.0f : 0.0f;

        // approximate sample path from here (u8-quantized anyway)
        float gx, gy, gz;
        {
#pragma clang fp contract(fast)
            gx = pxx * gsc + gsc;
            gy = pyy * gsc + gsc;
            gz = pzz * gsc + gsc;
        }
        int ix = (int)floorf(gx); ix = min(max(ix, 0), D - 2);
        int iy = (int)floorf(gy); iy = min(max(iy, 0), D - 2);
        int iz = (int)floorf(gz); iz = min(max(iz, 0), D - 2);
        float fx = fminf(fmaxf(gx - (float)ix, 0.0f), 1.0f);
        float fy = fminf(fmaxf(gy - (float)iy, 0.0f), 1.0f);
        float fz = fminf(fmaxf(gz - (float)iz, 0.0f), 1.0f);

        // u8 bilinear weights, packed to match entry byte order
        int wx1 = (int)(fx * 255.0f + 0.5f);
        int wy1 = (int)(fy * 255.0f + 0.5f);
        int wx0 = 255 - wx1, wy0 = 255 - wy1;
        unsigned p00 = (unsigned)((wx0 * wy0 + 128) >> 8);
        unsigned p10 = (unsigned)((wx1 * wy0 + 128) >> 8);
        unsigned p01 = (unsigned)((wx0 * wy1 + 128) >> 8);
        unsigned p11 = (unsigned)((wx1 * wy1 + 128) >> 8);
        unsigned wp = p00 | (p10 << 8) | (p01 << 16) | (p11 << 24);

        const uint4* p_ = vp + (iz * zs + iy * D + ix);
        uint4 A = p_[0];
        uint4 Bv = p_[zs];

        float rA = (float)udot4(A.x, wp), rB = (float)udot4(Bv.x, wp);
        float gA = (float)udot4(A.y, wp), gB = (float)udot4(Bv.y, wp);
        float bA = (float)udot4(A.z, wp), bB = (float)udot4(Bv.z, wp);
        float sA = (float)udot4(A.w, wp), sB = (float)udot4(Bv.w, wp);

        float rS, gS, bS, sw;
        {
#pragma clang fp contract(fast)
            rS = rA + fz * (rB - rA);
            gS = gA + fz * (gB - gA);
            bS = bA + fz * (bB - bA);
            sw = (sA + fz * (sB - sA)) * inv;
        }
        float contrib = (fminf(alpha + sw * DT, 1.0f) - alpha) * m;
        {
#pragma clang fp contract(fast)
            accr = accr + rS * contrib;   // raw scale; *inv folded out of loop
            accg = accg + gS * contrib;
            accb = accb + bS * contrib;
        }
        alpha = alpha + contrib;
        pxx = pxx + stx; pyy = pyy + sty; pzz = pzz + stz;  // exact chain
    }

    long hw = (long)H * W;
    long o = (long)b * 4 * hw + (long)y * W + x;
    out[o] = accr * inv;
    out[o + hw] = accg * inv;
    out[o + 2 * hw] = accb * inv;
    out[o + 3 * hw] = alpha;
}

// ---------------- fallback: whole-ray march on original fp32 layout ----------

__global__ __launch_bounds__(256) void raymarch_simple_kernel(
        const float* __restrict__ camrot, const float* __restrict__ campos,
        const float* __restrict__ focal, const float* __restrict__ princpt,
        const float* __restrict__ pixelcoords, const float* __restrict__ vol,
        float* __restrict__ out, int B, int H, int W, int D) {
#pragma clang fp contract(off)
    int x = blockIdx.x * blockDim.x + threadIdx.x;
    int y = blockIdx.y * blockDim.y + threadIdx.y;
    int b = blockIdx.z;
    if (x >= W || y >= H) return;

    Ray r = ray_setup(camrot, campos, focal, princpt, pixelcoords, b, y, x, H, W);

    float accr = 0.0f, accg = 0.0f, accb = 0.0f, alpha = 0.0f;
    float gmax = (float)(D - 1);
    long spatial = (long)D * D * D;
    long zstride = (long)D * D;
    const float* vb = vol + (long)b * 4 * spatial;
    float pxx = r.posx, pyy = r.posy, pzz = r.posz;

    for (int s = 0; s < r.n; ++s) {
        bool inside = (pxx > -1.0f) && (pxx < 1.0f) && (pyy > -1.0f) &&
                      (pyy < 1.0f) && (pzz > -1.0f) && (pzz < 1.0f);
        float m = inside ? 1.0f : 0.0f;
        float gx = fminf(fmaxf((pxx + 1.0f) * 0.5f * gmax, 0.0f), gmax);
        float gy = fminf(fmaxf((pyy + 1.0f) * 0.5f * gmax, 0.0f), gmax);
        float gz = fminf(fmaxf((pzz + 1.0f) * 0.5f * gmax, 0.0f), gmax);
        int ix0 = (int)floorf(gx); if (ix0 > D - 2) ix0 = D - 2;
        int iy0 = (int)floorf(gy); if (iy0 > D - 2) iy0 = D - 2;
        int iz0 = (int)floorf(gz); if (iz0 > D - 2) iz0 = D - 2;
        float fx = gx - (float)ix0;
        float fy = gy - (float)iy0;
        float fz = gz - (float)iz0;

        long s000 = (long)iz0 * zstride + (long)iy0 * D + ix0;
        float c[8][4];
        const long offs[8] = {s000, s000 + 1, s000 + D, s000 + D + 1,
                              s000 + zstride, s000 + zstride + 1,
                              s000 + zstride + D, s000 + zstride + D + 1};
        #pragma unroll
        for (int k = 0; k < 8; ++k) {
            c[k][0] = vb[offs[k]];
            c[k][1] = vb[offs[k] + spatial];
            c[k][2] = vb[offs[k] + 2 * spatial];
            c[k][3] = vb[offs[k] + 3 * spatial];
        }
        float wa = 1.0f - fx, wb = 1.0f - fy, wc = 1.0f - fz;
        float samp[4];
        #pragma unroll
        for (int ci = 0; ci < 4; ++ci) {
            float c00 = c[0][ci] * wa + c[1][ci] * fx;
            float c01 = c[2][ci] * wa + c[3][ci] * fx;
            float c10 = c[4][ci] * wa + c[5][ci] * fx;
            float c11 = c[6][ci] * wa + c[7][ci] * fx;
            float c0 = c00 * wb + c01 * fy;
            float c1 = c10 * wb + c11 * fy;
            samp[ci] = c0 * wc + c1 * fz;
        }
        float contrib = (fminf(alpha + samp[3] * DT, 1.0f) - alpha) * m;
        accr = accr + samp[0] * contrib;
        accg = accg + samp[1] * contrib;
        accb = accb + samp[2] * contrib;
        alpha = alpha + contrib;
        pxx = pxx + r.stx; pyy = pyy + r.sty; pzz = pzz + r.stz;
    }

    long hw = (long)H * W;
    long o = (long)b * 4 * hw + (long)y * W + x;
    out[o] = accr;
    out[o + hw] = accg;
    out[o + 2 * hw] = accb;
    out[o + 3 * hw] = alpha;
}

extern "C" void kernel_launch(void* const* d_in, const int* in_sizes, int n_in,
                              void* d_out, int out_size, void* d_ws, size_t ws_size,
                              hipStream_t stream) {
    const float* camrot = (const float*)d_in[0];
    const float* campos = (const float*)d_in[1];
    const float* focal = (const float*)d_in[2];
    const float* princpt = (const float*)d_in[3];
    const float* pixelcoords = (const float*)d_in[4];
    const float* volume = (const float*)d_in[5];
    float* out = (float*)d_out;

    int B = in_sizes[0] / 9;
    long spatial = (long)in_sizes[5] / (B * 4);  // D^3
    int D = (int)lround(cbrt((double)spatial));
    while ((long)D * D * D > spatial) D--;
    while ((long)(D + 1) * (D + 1) * (D + 1) <= spatial) D++;
    long hw = (long)in_sizes[4] / (B * 2);
    int H = (int)lround(sqrt((double)hw));
    int W = H;

    size_t vol_bytes = (size_t)B * spatial * sizeof(uint4);

    if (ws_size >= vol_bytes && D >= 2) {
        uint4* vol8 = (uint4*)d_ws;
        long nchunks = spatial >> 2;
        bool shfl_ok = ((D & 3) == 0) && ((64 % (D / 4)) == 0) &&
                       ((nchunks % 256) == 0);
        if (shfl_ok) {
            dim3 rgrd((unsigned)(nchunks / 256), B, 1);
            repack_u8x4_shfl_kernel<<<rgrd, dim3(256), 0, stream>>>(volume, vol8,
                                                                    spatial, D);
        } else if ((D & 3) == 0) {
            dim3 rgrd((unsigned)((nchunks + 255) / 256), B, 1);
            repack_u8x4_kernel<<<rgrd, dim3(256), 0, stream>>>(volume, vol8, spatial, D);
        } else {
            long total = (long)B * spatial;
            repack_u8_kernel<<<dim3((unsigned)((total + 255) / 256)), dim3(256), 0,
                               stream>>>(volume, vol8, total, spatial, D);
        }
        dim3 blk(16, 16, 1);
        dim3 grd((W + 15) / 16, (H + 15) / 16, B);
        if (D == 128) {
            raymarch_dot_kernel<128><<<grd, blk, 0, stream>>>(
                camrot, campos, focal, princpt, pixelcoords, vol8, out, B, H, W, D);
        } else {
            raymarch_dot_kernel<0><<<grd, blk, 0, stream>>>(
                camrot, campos, focal, princpt, pixelcoords, vol8, out, B, H, W, D);
        }
    } else {
        dim3 blk(16, 16, 1);
        dim3 grd((W + 15) / 16, (H + 15) / 16, B);
        raymarch_simple_kernel<<<grd, blk, 0, stream>>>(camrot, campos, focal, princpt,
                                                        pixelcoords, volume,
                                                        out, B, H, W, D);
    }
}

// Round 12
// 145.202 us; speedup vs baseline: 1.1701x; 1.0627x over previous
//
#include <hip/hip_runtime.h>
#include <math.h>

// The position/mask chain must replicate the numpy fp32 reference bit-exactly
// (no FMA contraction): the entry-face validity test (pos > -1) is knife-edge
// for every hitting ray. Sample math is u8-quantized and may contract.
#pragma clang fp contract(off)

#define DT 0.03125f
#define INV_DT 32.0f
#define NSTEPS 111

#if defined(__has_builtin)
#if __has_builtin(__builtin_amdgcn_udot4)
#define HAVE_UDOT4 1
#endif
#endif

__device__ __forceinline__ unsigned udot4(unsigned a, unsigned b) {
#ifdef HAVE_UDOT4
    return __builtin_amdgcn_udot4(a, b, 0u, false);
#else
    return (a & 0xffu) * (b & 0xffu)
         + ((a >> 8) & 0xffu) * ((b >> 8) & 0xffu)
         + ((a >> 16) & 0xffu) * ((b >> 16) & 0xffu)
         + ((a >> 24) & 0xffu) * ((b >> 24) & 0xffu);
#endif
}

// ---------------- u8 stencil-pair packing ----------------
// Entry (z,y,x) = 16B = 4 dwords (r,g,b,sigma); dword bytes:
//   [c(x0,y0), c(x1,y0), c(x0,y1), c(x1,y1)]  (x1=min(x+1,D-1), y1=min(y+1,D-1))
// Trilinear stencil = entry at z0 + entry at z0+1: 2 gathers/step.

__device__ __forceinline__ unsigned q8(float v) {
    return __float2uint_rn(fminf(fmaxf(v, 0.0f), 1.0f) * 255.0f);
}

// Repack with shfl neighbor fetch + LDS-staged COALESCED stores.
// R11 evidence: per-thread-contiguous stores (4 x uint4, lane stride 64B) left
// repack at 41us / 2.55 TB/s effective; stores were the scatter. Staging via
// LDS turns store instr k into 64 lanes x 16B contiguous.
// Valid when: D%4==0 && 64 % (D/4) == 0 && chunks-per-batch % 256 == 0.
__global__ __launch_bounds__(256) void repack_u8x4_lds_kernel(
        const float* __restrict__ vol, uint4* __restrict__ out,
        long spatial, int D) {
    long chunk = (long)blockIdx.x * 256 + threadIdx.x;
    long b = blockIdx.y;
    long s = chunk << 2;
    int zs = D * D;
    int z = (int)(s / zs);
    int rem = (int)(s - (long)z * zs);
    int y = rem / D;
    int x0 = rem - y * D;           // chunk never straddles a row (D%4==0)
    int y1 = (y < D - 1) ? y + 1 : y;
    bool last = (x0 + 4 >= D);      // row-end: x+1 clamps to D-1 (= va.w)

    const float* base = vol + b * 4 * spatial;
    uint4 e[4];
    #pragma unroll
    for (int ci = 0; ci < 4; ++ci) {
        const float* pa = base + (long)ci * spatial + (long)z * zs + y * D + x0;
        const float* pb = base + (long)ci * spatial + (long)z * zs + y1 * D + x0;
        float4 va = *(const float4*)pa;
        float4 vb = *(const float4*)pb;
        float na_sh = __shfl_down(va.x, 1, 64);   // lane i+1's first element
        float nb_sh = __shfl_down(vb.x, 1, 64);
        float na = last ? va.w : na_sh;           // row-end lanes override (also
        float nb = last ? vb.w : nb_sh;           // covers wave-boundary lanes)
        float ra[5] = {va.x, va.y, va.z, va.w, na};
        float rb[5] = {vb.x, vb.y, vb.z, vb.w, nb};
        #pragma unroll
        for (int k = 0; k < 4; ++k) {
            unsigned d = q8(ra[k]) | (q8(ra[k + 1]) << 8) |
                         (q8(rb[k]) << 16) | (q8(rb[k + 1]) << 24);
            ((unsigned*)&e[k])[ci] = d;
        }
    }

    // LDS transpose: local entry (4*tid+j) -> linear tile order, then
    // 4 fully-coalesced 16B/lane stores. +1 pad (257) keeps the transposed
    // read at ~2-way bank aliasing (free).
    __shared__ uint4 lds[4 * 257];
    int t = threadIdx.x;
    #pragma unroll
    for (int j = 0; j < 4; ++j) lds[j * 257 + t] = e[j];
    __syncthreads();
    uint4* o = out + b * spatial + ((long)blockIdx.x << 10);
    #pragma unroll
    for (int k = 0; k < 4; ++k) {
        // entry (k*256+t) was produced by thread (k*64 + t/4), slot (t&3)
        o[k * 256 + t] = lds[(t & 3) * 257 + k * 64 + (t >> 2)];
    }
}

// Fast repack without shfl/LDS (scalar neighbor loads). Requires D % 4 == 0.
__global__ __launch_bounds__(256) void repack_u8x4_kernel(const float* __restrict__ vol,
                                                          uint4* __restrict__ out,
                                                          long spatial, int D) {
    long chunk = (long)blockIdx.x * blockDim.x + threadIdx.x;
    long nchunks = spatial >> 2;
    if (chunk >= nchunks) return;
    long b = blockIdx.y;
    long s = chunk << 2;
    int zs = D * D;
    int z = (int)(s / zs);
    int rem = (int)(s - (long)z * zs);
    int y = rem / D;
    int x0 = rem - y * D;
    int y1 = (y < D - 1) ? y + 1 : y;

    const float* base = vol + b * 4 * spatial;
    uint4 e[4];
    #pragma unroll
    for (int ci = 0; ci < 4; ++ci) {
        const float* pa = base + (long)ci * spatial + (long)z * zs + y * D + x0;
        const float* pb = base + (long)ci * spatial + (long)z * zs + y1 * D + x0;
        float4 va = *(const float4*)pa;
        float4 vb = *(const float4*)pb;
        bool last = (x0 + 4 >= D);
        float na = last ? pa[3] : pa[4];
        float nb = last ? pb[3] : pb[4];
        float ra[5] = {va.x, va.y, va.z, va.w, na};
        float rb[5] = {vb.x, vb.y, vb.z, vb.w, nb};
        #pragma unroll
        for (int k = 0; k < 4; ++k) {
            unsigned d = q8(ra[k]) | (q8(ra[k + 1]) << 8) |
                         (q8(rb[k]) << 16) | (q8(rb[k + 1]) << 24);
            ((unsigned*)&e[k])[ci] = d;
        }
    }
    uint4* o = out + b * spatial + s;
    o[0] = e[0]; o[1] = e[1]; o[2] = e[2]; o[3] = e[3];
}

// Generic repack: one entry per thread (any D).
__global__ __launch_bounds__(256) void repack_u8_kernel(const float* __restrict__ vol,
                                                        uint4* __restrict__ out,
                                                        long total, long spatial, int D) {
    long idx = (long)blockIdx.x * blockDim.x + threadIdx.x;
    if (idx >= total) return;
    long b = idx / spatial;
    long s = idx - b * spatial;
    int zs = D * D;
    int z = (int)(s / zs);
    int rem = (int)(s - (long)z * zs);
    int y = rem / D;
    int x = rem - y * D;
    int x1 = (x < D - 1) ? x + 1 : x;
    int y1 = (y < D - 1) ? y + 1 : y;
    const float* base = vol + b * 4 * spatial;
    uint4 e;
    #pragma unroll
    for (int ci = 0; ci < 4; ++ci) {
        const float* p = base + (long)ci * spatial + (long)z * zs;
        unsigned d = q8(p[y * D + x]) | (q8(p[y * D + x1]) << 8) |
                     (q8(p[y1 * D + x]) << 16) | (q8(p[y1 * D + x1]) << 24);
        ((unsigned*)&e)[ci] = d;
    }
    out[idx] = e;
}

// ---------------- shared ray setup (bit-exact) ----------------

struct Ray {
    float posx, posy, posz;
    float stx, sty, stz;
    int n;   // conservative bound: steps >= n are provably invalid
};

__device__ __forceinline__ Ray ray_setup(const float* __restrict__ camrot,
                                         const float* __restrict__ campos,
                                         const float* __restrict__ focal,
                                         const float* __restrict__ princpt,
                                         const float* __restrict__ pixelcoords,
                                         int b, int y, int x, int H, int W) {
#pragma clang fp contract(off)
    long pidx = (((long)b * H + y) * W + x) * 2;
    float px = pixelcoords[pidx];
    float py = pixelcoords[pidx + 1];
    const float* R = camrot + b * 9;
    float cpx = campos[b * 3 + 0], cpy = campos[b * 3 + 1], cpz = campos[b * 3 + 2];
    float flx = focal[b * 2 + 0], fly = focal[b * 2 + 1];
    float prx = princpt[b * 2 + 0], pry = princpt[b * 2 + 1];

    float rx = (px - prx) / flx;
    float ry = (py - pry) / fly;
    float rz = 1.0f;
    float dx = R[0] * rx + R[3] * ry + R[6] * rz;
    float dy = R[1] * rx + R[4] * ry + R[7] * rz;
    float dz = R[2] * rx + R[5] * ry + R[8] * rz;
    float ss = dx * dx;
    ss = ss + dy * dy;
    ss = ss + dz * dz;
    float nrm = sqrtf(ss);
    dx = dx / nrm; dy = dy / nrm; dz = dz / nrm;

    float t1x = (-1.0f - cpx) / dx, t2x = (1.0f - cpx) / dx;
    float t1y = (-1.0f - cpy) / dy, t2y = (1.0f - cpy) / dy;
    float t1z = (-1.0f - cpz) / dz, t2z = (1.0f - cpz) / dz;
    float tmin = fmaxf(fminf(t1x, t2x), fmaxf(fminf(t1y, t2y), fminf(t1z, t2z)));
    float tmax = fminf(fmaxf(t1x, t2x), fminf(fmaxf(t1y, t2y), fmaxf(t1z, t2z)));
    bool hit = tmin < tmax;
    float t0 = fmaxf(hit ? tmin : 0.0f, 0.0f);

    Ray r;
    r.posx = cpx + dx * t0;
    r.posy = cpy + dy * t0;
    r.posz = cpz + dz * t0;
    r.stx = dx * DT; r.sty = dy * DT; r.stz = dz * DT;

    // valid step s needs t0 + s*DT < tmax; +4 slack dwarfs fp drift over <=111
    // rounded adds. NaN span -> fminf selects NSTEPS (conservative). Steps in
    // [n, NSTEPS) are provably invalid (mask would be 0) so skipping is exact.
    float span = (tmax - t0) * INV_DT + 4.0f;
    span = fminf(span, (float)NSTEPS);
    r.n = (hit && span > 0.0f) ? (int)span : 0;
    return r;
}

// ---------------- march: u8 stencil-pair volume + v_dot4 sampling ----------
// (R9 structure verbatim: single ray/thread, 256-thread blocks, 8 waves/CU.
//  Do NOT re-attempt intra-thread pipelining or multi-ray ILP — the scheduler
//  collapses the buffers and serializes; measured 4x in R3/R4/R6/R10.)

template <int DD>
__global__ __launch_bounds__(256, 2) void raymarch_dot_kernel(
        const float* __restrict__ camrot, const float* __restrict__ campos,
        const float* __restrict__ focal, const float* __restrict__ princpt,
        const float* __restrict__ pixelcoords, const uint4* __restrict__ vol,
        float* __restrict__ out, int B, int H, int W, int Drt) {
#pragma clang fp contract(off)
    const int D = (DD > 0) ? DD : Drt;
    int x = blockIdx.x * 16 + threadIdx.x;
    int y = blockIdx.y * 16 + threadIdx.y;
    int b = blockIdx.z;
    if (x >= W || y >= H) return;

    Ray r = ray_setup(camrot, campos, focal, princpt, pixelcoords, b, y, x, H, W);

    float accr = 0.0f, accg = 0.0f, accb = 0.0f, alpha = 0.0f;
    const float gsc = 0.5f * (float)(D - 1);        // g = pos*gsc + gsc
    const float inv = 1.0f / (255.0f * 255.0f);
    const int zs = D * D;
    const uint4* vp = vol + (long)b * ((long)zs * D);
    float pxx = r.posx, pyy = r.posy, pzz = r.posz;
    float stx = r.stx, sty = r.sty, stz = r.stz;

    for (int s = 0; s < r.n; ++s) {
        // exact mask (file-default contract(off), same op order as reference)
        bool inside = (pxx > -1.0f) && (pxx < 1.0f) && (pyy > -1.0f) &&
                      (pyy < 1.0f) && (pzz > -1.0f) && (pzz < 1.0f);
        float m = inside ? 1.0f : 0.0f;

        // approximate sample path from here (u8-quantized anyway)
        float gx, gy, gz;
        {
#pragma clang fp contract(fast)
            gx = pxx * gsc + gsc;
            gy = pyy * gsc + gsc;
            gz = pzz * gsc + gsc;
        }
        int ix = (int)floorf(gx); ix = min(max(ix, 0), D - 2);
        int iy = (int)floorf(gy); iy = min(max(iy, 0), D - 2);
        int iz = (int)floorf(gz); iz = min(max(iz, 0), D - 2);
        float fx = fminf(fmaxf(gx - (float)ix, 0.0f), 1.0f);
        float fy = fminf(fmaxf(gy - (float)iy, 0.0f), 1.0f);
        float fz = fminf(fmaxf(gz - (float)iz, 0.0f), 1.0f);

        // u8 bilinear weights, packed to match entry byte order
        int wx1 = (int)(fx * 255.0f + 0.5f);
        int wy1 = (int)(fy * 255.0f + 0.5f);
        int wx0 = 255 - wx1, wy0 = 255 - wy1;
        unsigned p00 = (unsigned)((wx0 * wy0 + 128) >> 8);
        unsigned p10 = (unsigned)((wx1 * wy0 + 128) >> 8);
        unsigned p01 = (unsigned)((wx0 * wy1 + 128) >> 8);
        unsigned p11 = (unsigned)((wx1 * wy1 + 128) >> 8);
        unsigned wp = p00 | (p10 << 8) | (p01 << 16) | (p11 << 24);

        const uint4* p_ = vp + (iz * zs + iy * D + ix);
        uint4 A = p_[0];
        uint4 Bv = p_[zs];

        float rA = (float)udot4(A.x, wp), rB = (float)udot4(Bv.x, wp);
        float gA = (float)udot4(A.y, wp), gB = (float)udot4(Bv.y, wp);
        float bA = (float)udot4(A.z, wp), bB = (float)udot4(Bv.z, wp);
        float sA = (float)udot4(A.w, wp), sB = (float)udot4(Bv.w, wp);

        float rS, gS, bS, sw;
        {
#pragma clang fp contract(fast)
            rS = rA + fz * (rB - rA);
            gS = gA + fz * (gB - gA);
            bS = bA + fz * (bB - bA);
            sw = (sA + fz * (sB - sA)) * inv;
        }
        float contrib = (fminf(alpha + sw * DT, 1.0f) - alpha) * m;
        {
#pragma clang fp contract(fast)
            accr = accr + rS * contrib;   // raw scale; *inv folded out of loop
            accg = accg + gS * contrib;
            accb = accb + bS * contrib;
        }
        alpha = alpha + contrib;
        pxx = pxx + stx; pyy = pyy + sty; pzz = pzz + stz;  // exact chain
    }

    long hw = (long)H * W;
    long o = (long)b * 4 * hw + (long)y * W + x;
    out[o] = accr * inv;
    out[o + hw] = accg * inv;
    out[o + 2 * hw] = accb * inv;
    out[o + 3 * hw] = alpha;
}

// ---------------- fallback: whole-ray march on original fp32 layout ----------

__global__ __launch_bounds__(256) void raymarch_simple_kernel(
        const float* __restrict__ camrot, const float* __restrict__ campos,
        const float* __restrict__ focal, const float* __restrict__ princpt,
        const float* __restrict__ pixelcoords, const float* __restrict__ vol,
        float* __restrict__ out, int B, int H, int W, int D) {
#pragma clang fp contract(off)
    int x = blockIdx.x * blockDim.x + threadIdx.x;
    int y = blockIdx.y * blockDim.y + threadIdx.y;
    int b = blockIdx.z;
    if (x >= W || y >= H) return;

    Ray r = ray_setup(camrot, campos, focal, princpt, pixelcoords, b, y, x, H, W);

    float accr = 0.0f, accg = 0.0f, accb = 0.0f, alpha = 0.0f;
    float gmax = (float)(D - 1);
    long spatial = (long)D * D * D;
    long zstride = (long)D * D;
    const float* vb = vol + (long)b * 4 * spatial;
    float pxx = r.posx, pyy = r.posy, pzz = r.posz;

    for (int s = 0; s < r.n; ++s) {
        bool inside = (pxx > -1.0f) && (pxx < 1.0f) && (pyy > -1.0f) &&
                      (pyy < 1.0f) && (pzz > -1.0f) && (pzz < 1.0f);
        float m = inside ? 1.0f : 0.0f;
        float gx = fminf(fmaxf((pxx + 1.0f) * 0.5f * gmax, 0.0f), gmax);
        float gy = fminf(fmaxf((pyy + 1.0f) * 0.5f * gmax, 0.0f), gmax);
        float gz = fminf(fmaxf((pzz + 1.0f) * 0.5f * gmax, 0.0f), gmax);
        int ix0 = (int)floorf(gx); if (ix0 > D - 2) ix0 = D - 2;
        int iy0 = (int)floorf(gy); if (iy0 > D - 2) iy0 = D - 2;
        int iz0 = (int)floorf(gz); if (iz0 > D - 2) iz0 = D - 2;
        float fx = gx - (float)ix0;
        float fy = gy - (float)iy0;
        float fz = gz - (float)iz0;

        long s000 = (long)iz0 * zstride + (long)iy0 * D + ix0;
        float c[8][4];
        const long offs[8] = {s000, s000 + 1, s000 + D, s000 + D + 1,
                              s000 + zstride, s000 + zstride + 1,
                              s000 + zstride + D, s000 + zstride + D + 1};
        #pragma unroll
        for (int k = 0; k < 8; ++k) {
            c[k][0] = vb[offs[k]];
            c[k][1] = vb[offs[k] + spatial];
            c[k][2] = vb[offs[k] + 2 * spatial];
            c[k][3] = vb[offs[k] + 3 * spatial];
        }
        float wa = 1.0f - fx, wb = 1.0f - fy, wc = 1.0f - fz;
        float samp[4];
        #pragma unroll
        for (int ci = 0; ci < 4; ++ci) {
            float c00 = c[0][ci] * wa + c[1][ci] * fx;
            float c01 = c[2][ci] * wa + c[3][ci] * fx;
            float c10 = c[4][ci] * wa + c[5][ci] * fx;
            float c11 = c[6][ci] * wa + c[7][ci] * fx;
            float c0 = c00 * wb + c01 * fy;
            float c1 = c10 * wb + c11 * fy;
            samp[ci] = c0 * wc + c1 * fz;
        }
        float contrib = (fminf(alpha + samp[3] * DT, 1.0f) - alpha) * m;
        accr = accr + samp[0] * contrib;
        accg = accg + samp[1] * contrib;
        accb = accb + samp[2] * contrib;
        alpha = alpha + contrib;
        pxx = pxx + r.stx; pyy = pyy + r.sty; pzz = pzz + r.stz;
    }

    long hw = (long)H * W;
    long o = (long)b * 4 * hw + (long)y * W + x;
    out[o] = accr;
    out[o + hw] = accg;
    out[o + 2 * hw] = accb;
    out[o + 3 * hw] = alpha;
}

extern "C" void kernel_launch(void* const* d_in, const int* in_sizes, int n_in,
                              void* d_out, int out_size, void* d_ws, size_t ws_size,
                              hipStream_t stream) {
    const float* camrot = (const float*)d_in[0];
    const float* campos = (const float*)d_in[1];
    const float* focal = (const float*)d_in[2];
    const float* princpt = (const float*)d_in[3];
    const float* pixelcoords = (const float*)d_in[4];
    const float* volume = (const float*)d_in[5];
    float* out = (float*)d_out;

    int B = in_sizes[0] / 9;
    long spatial = (long)in_sizes[5] / (B * 4);  // D^3
    int D = (int)lround(cbrt((double)spatial));
    while ((long)D * D * D > spatial) D--;
    while ((long)(D + 1) * (D + 1) * (D + 1) <= spatial) D++;
    long hw = (long)in_sizes[4] / (B * 2);
    int H = (int)lround(sqrt((double)hw));
    int W = H;

    size_t vol_bytes = (size_t)B * spatial * sizeof(uint4);

    if (ws_size >= vol_bytes && D >= 2) {
        uint4* vol8 = (uint4*)d_ws;
        long nchunks = spatial >> 2;
        bool lds_ok = ((D & 3) == 0) && ((64 % (D / 4)) == 0) &&
                      ((nchunks % 256) == 0);
        if (lds_ok) {
            dim3 rgrd((unsigned)(nchunks / 256), B, 1);
            repack_u8x4_lds_kernel<<<rgrd, dim3(256), 0, stream>>>(volume, vol8,
                                                                   spatial, D);
        } else if ((D & 3) == 0) {
            dim3 rgrd((unsigned)((nchunks + 255) / 256), B, 1);
            repack_u8x4_kernel<<<rgrd, dim3(256), 0, stream>>>(volume, vol8, spatial, D);
        } else {
            long total = (long)B * spatial;
            repack_u8_kernel<<<dim3((unsigned)((total + 255) / 256)), dim3(256), 0,
                               stream>>>(volume, vol8, total, spatial, D);
        }
        dim3 blk(16, 16, 1);
        dim3 grd((W + 15) / 16, (H + 15) / 16, B);
        if (D == 128) {
            raymarch_dot_kernel<128><<<grd, blk, 0, stream>>>(
                camrot, campos, focal, princpt, pixelcoords, vol8, out, B, H, W, D);
        } else {
            raymarch_dot_kernel<0><<<grd, blk, 0, stream>>>(
                camrot, campos, focal, princpt, pixelcoords, vol8, out, B, H, W, D);
        }
    } else {
        dim3 blk(16, 16, 1);
        dim3 grd((W + 15) / 16, (H + 15) / 16, B);
        raymarch_simple_kernel<<<grd, blk, 0, stream>>>(camrot, campos, focal, princpt,
                                                        pixelcoords, volume,
                                                        out, B, H, W, D);
    }
}